// Round 1
// baseline (466.694 us; speedup 1.0000x reference)
//
#include <hip/hip_runtime.h>
#include <math.h>

// ---------------- workspace layout (floats) ----------------
// x (relu conv1 out): 512*1024          @ 0
// bbox_pred:          36*1024           @ 524288
// proposals:          9216*4            @ 561152
#define WS_X_OFF    0
#define WS_BBOX_OFF 524288
#define WS_PROP_OFF 561152

// ================= conv 3x3 (256->512, 32x32, pad 1) + ReLU =================
// one block per output channel, 256 threads, thread = (row, 4 adjacent x).
// fp64 accumulation for max closeness to exact (NMS decisions depend on it).
__global__ __launch_bounds__(256) void conv3x3_relu_k(
    const float* __restrict__ feat, const float* __restrict__ w,
    const float* __restrict__ bias, float* __restrict__ xout)
{
  constexpr int TC = 8;          // input-channel chunk staged in LDS
  constexpr int PITCH = 33;      // +1 pad: breaks 8-way bank conflict
  __shared__ float wl[256 * 9];
  __shared__ float il[TC * 32 * PITCH];
  const int co = blockIdx.x, tid = threadIdx.x;
  for (int i = tid; i < 2304; i += 256) wl[i] = w[co * 2304 + i];
  const int y = tid >> 3, x0 = (tid & 7) << 2;
  double a0 = 0.0, a1 = 0.0, a2 = 0.0, a3 = 0.0;
  for (int cc = 0; cc < 256; cc += TC) {
    __syncthreads();
    for (int i = tid; i < TC * 1024; i += 256) {
      int ch = i >> 10, px = i & 1023;
      il[ch * (32 * PITCH) + (px >> 5) * PITCH + (px & 31)] =
          feat[((cc + ch) << 10) + px];
    }
    __syncthreads();
    for (int cl = 0; cl < TC; ++cl) {
      const float* wr = &wl[(cc + cl) * 9];
      const float* ir = &il[cl * (32 * PITCH)];
      #pragma unroll
      for (int ky = 0; ky < 3; ++ky) {
        const int yy = y + ky - 1;
        const bool yv = (unsigned)yy < 32u;
        double v[6];
        #pragma unroll
        for (int j = 0; j < 6; ++j) {
          int xx = x0 - 1 + j;
          bool ok = yv && ((unsigned)xx < 32u);
          int idx = ok ? (yy * PITCH + xx) : 0;   // clamp BEFORE the LDS read
          float t = ir[idx];
          v[j] = ok ? (double)t : 0.0;
        }
        const double w0 = (double)wr[ky * 3 + 0];
        const double w1 = (double)wr[ky * 3 + 1];
        const double w2 = (double)wr[ky * 3 + 2];
        a0 += v[0] * w0 + v[1] * w1 + v[2] * w2;
        a1 += v[1] * w0 + v[2] * w1 + v[3] * w2;
        a2 += v[2] * w0 + v[3] * w1 + v[4] * w2;
        a3 += v[3] * w0 + v[4] * w1 + v[5] * w2;
      }
    }
  }
  const double b = (double)bias[co];
  float4 r;
  r.x = (float)fmax(a0 + b, 0.0);
  r.y = (float)fmax(a1 + b, 0.0);
  r.z = (float)fmax(a2 + b, 0.0);
  r.w = (float)fmax(a3 + b, 0.0);
  *(float4*)&xout[(co << 10) + (y << 5) + x0] = r;
}

// ================= 1x1 heads: cls (18ch -> sigmoid -> out) + bbox (36ch) ====
__global__ __launch_bounds__(256) void head1x1_k(
    const float* __restrict__ x,
    const float* __restrict__ cls_w, const float* __restrict__ cls_b,
    const float* __restrict__ bbox_w, const float* __restrict__ bbox_b,
    float* __restrict__ out, float* __restrict__ bbox_out)
{
  __shared__ float wl[512];
  const int bid = blockIdx.x;
  const int co = bid >> 2;                       // 0..53
  const int px = ((bid & 3) << 8) | threadIdx.x; // 0..1023
  const bool is_cls = co < 18;
  const float* wsrc = is_cls ? (cls_w + co * 512) : (bbox_w + (co - 18) * 512);
  for (int i = threadIdx.x; i < 512; i += 256) wl[i] = wsrc[i];
  __syncthreads();
  double acc0 = 0.0, acc1 = 0.0, acc2 = 0.0, acc3 = 0.0;
  #pragma unroll 4
  for (int c = 0; c < 512; c += 4) {
    acc0 += (double)x[((c + 0) << 10) | px] * (double)wl[c + 0];
    acc1 += (double)x[((c + 1) << 10) | px] * (double)wl[c + 1];
    acc2 += (double)x[((c + 2) << 10) | px] * (double)wl[c + 2];
    acc3 += (double)x[((c + 3) << 10) | px] * (double)wl[c + 3];
  }
  double acc = ((acc0 + acc1) + (acc2 + acc3)) +
               (double)(is_cls ? cls_b[co] : bbox_b[co - 18]);
  if (is_cls)
    out[36864 + (co << 10) + px] = (float)(1.0 / (1.0 + exp(-acc)));
  else
    bbox_out[((co - 18) << 10) + px] = (float)acc;
}

// ================= anchors + box decode + clip ==============================
// box r: deltas = bbox_flat[4r..4r+3]; anchor: cell=r/9 (iy*32+ix), a=r%9
// (ratio-major over scales), torchvision rounding (round-half-even).
__global__ __launch_bounds__(256) void proposals_k(
    const float* __restrict__ bbox, const int* __restrict__ imgsz,
    float* __restrict__ props)
{
  const int r = blockIdx.x * 256 + threadIdx.x;
  if (r >= 9216) return;
  const float4 d = ((const float4*)bbox)[r];
  const int cell = r / 9, a = r - cell * 9;
  const int ix = cell & 31, iy = cell >> 5;
  const int ri = a / 3, si = a - ri * 3;
  const double ratio = (ri == 0) ? 0.5 : (ri == 1 ? 1.0 : 2.0);
  const double scale = (si == 0) ? 128.0 : (si == 1 ? 256.0 : 512.0);
  const double hr = sqrt(ratio), wr = 1.0 / hr;
  const double bx = nearbyint(wr * scale * 0.5);   // round(ws/2), half-even
  const double by = nearbyint(hr * scale * 0.5);
  // anchor = [sx-bx, sy-by, sx+bx, sy+by] -> w=2bx, h=2by, cx=sx, cy=sy
  const double cx = ix * 16.0, cy = iy * 16.0;
  const double w = 2.0 * bx, h = 2.0 * by;
  const double pcx = (double)d.x * w + cx;
  const double pcy = (double)d.y * h + cy;
  const double pw = exp((double)d.z) * w;
  const double ph = exp((double)d.w) * h;
  const double im = (double)imgsz[0];
  float4 o;
  o.x = (float)fmin(fmax(pcx - 0.5 * pw, 0.0), im);
  o.y = (float)fmin(fmax(pcy - 0.5 * ph, 0.0), im);
  o.z = (float)fmin(fmax(pcx + 0.5 * pw, 0.0), im);
  o.w = (float)fmin(fmax(pcy + 0.5 * ph, 0.0), im);
  ((float4*)props)[r] = o;
}

// ================= exact sequential NMS via selection-max ===================
// single block, 1024 threads; 9 boxes/thread held in registers.
// key = (score_bits<<32) | (0x7FFFFFFF - r)  -> max = highest score, tie: min r
// (matches stable argsort(-scores)). Each iteration keeps the max-alive box
// and suppresses alive boxes with IoU > 0.3 — identical to reference fori_loop.
__global__ __launch_bounds__(1024) void nms_k(
    const float* __restrict__ props, float* __restrict__ out)
{
  __shared__ unsigned long long wmax[16];
  __shared__ unsigned long long curKeyS;
  __shared__ float4 curBoxS;
  const int tid = threadIdx.x;
  unsigned long long key[9];
  float4 box[9];
  #pragma unroll
  for (int j = 0; j < 9; ++j) {
    const int r = tid + (j << 10);
    box[j] = ((const float4*)props)[r];
    const int a = r >> 10, pos = r & 1023;                 // fg_scores layout
    const float s = out[36864 + ((2 * a + 1) << 10) + pos]; // probs ch 2a+1
    key[j] = ((unsigned long long)__float_as_uint(s) << 32) |
             (unsigned)(0x7FFFFFFF - r);
  }
  unsigned kept = 0;
  for (int iter = 0; iter < 9216; ++iter) {
    unsigned long long m = 0;
    #pragma unroll
    for (int j = 0; j < 9; ++j) m = key[j] > m ? key[j] : m;
    #pragma unroll
    for (int off = 32; off; off >>= 1) {
      unsigned long long o = __shfl_down(m, off, 64);
      if (o > m) m = o;
    }
    if ((tid & 63) == 0) wmax[tid >> 6] = m;
    __syncthreads();
    if (tid < 64) {
      unsigned long long mm = (tid < 16) ? wmax[tid] : 0ULL;
      #pragma unroll
      for (int off = 8; off; off >>= 1) {
        unsigned long long o = __shfl_down(mm, off, 64);
        if (o > mm) mm = o;
      }
      if (tid == 0) curKeyS = mm;
    }
    __syncthreads();
    const unsigned long long K = curKeyS;
    if (K == 0) break;                 // uniform: everyone decided
    #pragma unroll
    for (int j = 0; j < 9; ++j) {
      if (key[j] == K) { curBoxS = box[j]; key[j] = 0; kept |= 1u << j; }
    }
    __syncthreads();
    const float4 cb = curBoxS;
    const float areaC = (cb.z - cb.x) * (cb.w - cb.y);
    #pragma unroll
    for (int j = 0; j < 9; ++j) {
      if (key[j]) {
        const float4 b = box[j];
        const float ix1 = fmaxf(b.x, cb.x), iy1 = fmaxf(b.y, cb.y);
        const float ix2 = fminf(b.z, cb.z), iy2 = fminf(b.w, cb.w);
        const float iw = fmaxf(ix2 - ix1, 0.0f), ih = fmaxf(iy2 - iy1, 0.0f);
        const float inter = __fmul_rn(iw, ih);
        const float areaB = (b.z - b.x) * (b.w - b.y);
        const float denom = __fadd_rn(__fsub_rn(__fadd_rn(areaB, areaC), inter), 1e-9f);
        if (__fdiv_rn(inter, denom) > 0.3f) key[j] = 0;
      }
    }
    // next iteration's __syncthreads() orders curBoxS reuse
  }
  #pragma unroll
  for (int j = 0; j < 9; ++j) {
    const int r = tid + (j << 10);
    const bool kp = (kept >> j) & 1u;
    float4 ob = box[j];
    if (!kp) { ob.x = 0.f; ob.y = 0.f; ob.z = 0.f; ob.w = 0.f; }
    ((float4*)out)[r] = ob;               // proposals * keep
    out[55296 + r] = kp ? 1.0f : 0.0f;    // keep mask as float
  }
}

// ============================================================================
extern "C" void kernel_launch(void* const* d_in, const int* in_sizes, int n_in,
                              void* d_out, int out_size, void* d_ws, size_t ws_size,
                              hipStream_t stream)
{
  const float* feat   = (const float*)d_in[0];
  const int*   imgsz  = (const int*)d_in[1];
  const float* conv_w = (const float*)d_in[2];
  const float* conv_b = (const float*)d_in[3];
  const float* cls_w  = (const float*)d_in[4];
  const float* cls_b  = (const float*)d_in[5];
  const float* bbox_w = (const float*)d_in[6];
  const float* bbox_b = (const float*)d_in[7];
  float* out  = (float*)d_out;
  float* ws   = (float*)d_ws;
  float* x     = ws + WS_X_OFF;
  float* bbox  = ws + WS_BBOX_OFF;
  float* props = ws + WS_PROP_OFF;

  hipLaunchKernelGGL(conv3x3_relu_k, dim3(512), dim3(256), 0, stream,
                     feat, conv_w, conv_b, x);
  hipLaunchKernelGGL(head1x1_k, dim3(216), dim3(256), 0, stream,
                     x, cls_w, cls_b, bbox_w, bbox_b, out, bbox);
  hipLaunchKernelGGL(proposals_k, dim3(36), dim3(256), 0, stream,
                     bbox, imgsz, props);
  hipLaunchKernelGGL(nms_k, dim3(1), dim3(1024), 0, stream,
                     props, out);
}

// Round 2
// 454.652 us; speedup vs baseline: 1.0265x; 1.0265x over previous
//
#include <hip/hip_runtime.h>
#include <math.h>

// ---------------- workspace layout (floats) ----------------
#define WS_X_OFF    0
#define WS_BBOX_OFF 524288
#define WS_PROP_OFF 561152

// ================= conv 3x3 (256->512, 32x32, pad 1) + ReLU =================
// one block per output channel, 256 threads, thread = (row, 4 adjacent x).
// fp64 accumulation (NMS keep decisions require near-exact logits/deltas).
// Halo-padded fp32 input tile in LDS (zero border -> no bounds checks),
// weights converted to fp64 in LDS once per block.
#define CONV_TC    8
#define CONV_PITCH 38              // even (float2 aligned), !=0 mod 4 spreads banks
#define CONV_CHS   (34 * CONV_PITCH)

__global__ __launch_bounds__(256) void conv3x3_relu_k(
    const float* __restrict__ feat, const float* __restrict__ w,
    const float* __restrict__ bias, float* __restrict__ xout)
{
  __shared__ float  il[CONV_TC * CONV_CHS];  // 41,344 B
  __shared__ double wl[2304];                // 18,432 B
  const int co = blockIdx.x, tid = threadIdx.x;
  for (int i = tid; i < CONV_TC * CONV_CHS; i += 256) il[i] = 0.0f;   // halo zeros
  for (int i = tid; i < 2304; i += 256) wl[i] = (double)w[co * 2304 + i];
  const int y = tid >> 3, x0 = (tid & 7) << 2;
  double a0 = 0.0, a1 = 0.0, a2 = 0.0, a3 = 0.0;
  for (int cc = 0; cc < 256; cc += CONV_TC) {
    __syncthreads();                          // prev compute done / init done
    for (int i = tid; i < CONV_TC * 1024; i += 256) {
      const int ch = i >> 10, px = i & 1023;
      il[ch * CONV_CHS + ((px >> 5) + 1) * CONV_PITCH + (px & 31) + 1] =
          feat[((cc + ch) << 10) + px];
    }
    __syncthreads();
    #pragma unroll
    for (int cl = 0; cl < CONV_TC; ++cl) {
      const float*  ir = &il[cl * CONV_CHS + y * CONV_PITCH + x0];
      const double* wp = &wl[(cc + cl) * 9];
      #pragma unroll
      for (int ky = 0; ky < 3; ++ky) {
        const float2* p = (const float2*)(ir + ky * CONV_PITCH);  // 8B aligned
        const float2 q0 = p[0], q1 = p[1], q2 = p[2];
        const double d0 = (double)q0.x, d1 = (double)q0.y;
        const double d2 = (double)q1.x, d3 = (double)q1.y;
        const double d4 = (double)q2.x, d5 = (double)q2.y;
        const double w0 = wp[3 * ky + 0], w1 = wp[3 * ky + 1], w2 = wp[3 * ky + 2];
        a0 += d0 * w0 + d1 * w1 + d2 * w2;
        a1 += d1 * w0 + d2 * w1 + d3 * w2;
        a2 += d2 * w0 + d3 * w1 + d4 * w2;
        a3 += d3 * w0 + d4 * w1 + d5 * w2;
      }
    }
  }
  const double b = (double)bias[co];
  float4 r;
  r.x = (float)fmax(a0 + b, 0.0);
  r.y = (float)fmax(a1 + b, 0.0);
  r.z = (float)fmax(a2 + b, 0.0);
  r.w = (float)fmax(a3 + b, 0.0);
  *(float4*)&xout[(co << 10) + (y << 5) + x0] = r;
}

// ================= 1x1 heads: cls (18ch -> sigmoid -> out) + bbox (36ch) ====
__global__ __launch_bounds__(256) void head1x1_k(
    const float* __restrict__ x,
    const float* __restrict__ cls_w, const float* __restrict__ cls_b,
    const float* __restrict__ bbox_w, const float* __restrict__ bbox_b,
    float* __restrict__ out, float* __restrict__ bbox_out)
{
  __shared__ float wl[512];
  const int bid = blockIdx.x;
  const int co = bid >> 2;                       // 0..53
  const int px = ((bid & 3) << 8) | threadIdx.x; // 0..1023
  const bool is_cls = co < 18;
  const float* wsrc = is_cls ? (cls_w + co * 512) : (bbox_w + (co - 18) * 512);
  for (int i = threadIdx.x; i < 512; i += 256) wl[i] = wsrc[i];
  __syncthreads();
  double acc0 = 0.0, acc1 = 0.0, acc2 = 0.0, acc3 = 0.0;
  #pragma unroll 4
  for (int c = 0; c < 512; c += 4) {
    acc0 += (double)x[((c + 0) << 10) | px] * (double)wl[c + 0];
    acc1 += (double)x[((c + 1) << 10) | px] * (double)wl[c + 1];
    acc2 += (double)x[((c + 2) << 10) | px] * (double)wl[c + 2];
    acc3 += (double)x[((c + 3) << 10) | px] * (double)wl[c + 3];
  }
  double acc = ((acc0 + acc1) + (acc2 + acc3)) +
               (double)(is_cls ? cls_b[co] : bbox_b[co - 18]);
  if (is_cls)
    out[36864 + (co << 10) + px] = (float)(1.0 / (1.0 + exp(-acc)));
  else
    bbox_out[((co - 18) << 10) + px] = (float)acc;
}

// ================= anchors + box decode + clip ==============================
__global__ __launch_bounds__(256) void proposals_k(
    const float* __restrict__ bbox, const int* __restrict__ imgsz,
    float* __restrict__ props)
{
  const int r = blockIdx.x * 256 + threadIdx.x;
  if (r >= 9216) return;
  const float4 d = ((const float4*)bbox)[r];
  const int cell = r / 9, a = r - cell * 9;
  const int ix = cell & 31, iy = cell >> 5;
  const int ri = a / 3, si = a - ri * 3;
  const double ratio = (ri == 0) ? 0.5 : (ri == 1 ? 1.0 : 2.0);
  const double scale = (si == 0) ? 128.0 : (si == 1 ? 256.0 : 512.0);
  const double hr = sqrt(ratio), wr = 1.0 / hr;
  const double bx = nearbyint(wr * scale * 0.5);
  const double by = nearbyint(hr * scale * 0.5);
  const double cx = ix * 16.0, cy = iy * 16.0;
  const double w = 2.0 * bx, h = 2.0 * by;
  const double pcx = (double)d.x * w + cx;
  const double pcy = (double)d.y * h + cy;
  const double pw = exp((double)d.z) * w;
  const double ph = exp((double)d.w) * h;
  const double im = (double)imgsz[0];
  float4 o;
  o.x = (float)fmin(fmax(pcx - 0.5 * pw, 0.0), im);
  o.y = (float)fmin(fmax(pcy - 0.5 * ph, 0.0), im);
  o.z = (float)fmin(fmax(pcx + 0.5 * pw, 0.0), im);
  o.w = (float)fmin(fmax(pcy + 0.5 * ph, 0.0), im);
  ((float4*)props)[r] = o;
}

// ================= exact sequential NMS via selection-max ===================
// 1024 threads, 9 boxes/thread in registers.
// key = (score_bits<<32) | (0x7FFFFFFF - r) -> max = best score, tie: min r.
// Per iter: wave shfl-reduce -> wmax[16] -> barrier -> ALL threads scan the
// 16 entries for K (uniform) + owner publishes box -> barrier -> suppress.
// IoU decision: fp64 multiply-compare (more exact than reference fp32 div).
__global__ __launch_bounds__(1024) void nms_k(
    const float* __restrict__ props, float* __restrict__ out)
{
  __shared__ unsigned long long wmax[16];
  __shared__ float4 curBoxS;
  const int tid = threadIdx.x, wid = tid >> 6, lane = tid & 63;
  unsigned long long key[9];
  float4 box[9];
  #pragma unroll
  for (int j = 0; j < 9; ++j) {
    const int r = tid + (j << 10);
    box[j] = ((const float4*)props)[r];
    const int a = r >> 10, pos = r & 1023;                  // fg_scores layout
    const float s = out[36864 + ((2 * a + 1) << 10) + pos]; // probs ch 2a+1
    key[j] = ((unsigned long long)__float_as_uint(s) << 32) |
             (unsigned)(0x7FFFFFFF - r);
  }
  unsigned kept = 0;
  for (;;) {
    unsigned long long m = key[0];
    #pragma unroll
    for (int j = 1; j < 9; ++j) m = key[j] > m ? key[j] : m;
    #pragma unroll
    for (int off = 32; off; off >>= 1) {
      const unsigned long long o = __shfl_down(m, off, 64);
      if (o > m) m = o;
    }
    if (lane == 0) wmax[wid] = m;
    __syncthreads();
    unsigned long long K = wmax[0];
    #pragma unroll
    for (int wv = 1; wv < 16; ++wv) { const unsigned long long t = wmax[wv]; if (t > K) K = t; }
    if (K == 0) break;                               // uniform across block
    #pragma unroll
    for (int j = 0; j < 9; ++j)
      if (key[j] == K) { curBoxS = box[j]; key[j] = 0; kept |= 1u << j; }
    __syncthreads();
    const float4 cb = curBoxS;
    const float areaC = (cb.z - cb.x) * (cb.w - cb.y);
    #pragma unroll
    for (int j = 0; j < 9; ++j) {
      if (key[j]) {
        const float4 b = box[j];
        const float ix1 = fmaxf(b.x, cb.x), iy1 = fmaxf(b.y, cb.y);
        const float ix2 = fminf(b.z, cb.z), iy2 = fminf(b.w, cb.w);
        const float iw = fmaxf(ix2 - ix1, 0.0f), ih = fmaxf(iy2 - iy1, 0.0f);
        const float areaB = (b.z - b.x) * (b.w - b.y);
        const double inter = (double)iw * (double)ih;
        const double uni = (double)areaB + (double)areaC - inter + 1e-9;
        if (inter > 0.3 * uni) key[j] = 0;
      }
    }
    // next iteration's first __syncthreads orders wmax reuse
  }
  #pragma unroll
  for (int j = 0; j < 9; ++j) {
    const int r = tid + (j << 10);
    const bool kp = (kept >> j) & 1u;
    float4 ob = box[j];
    if (!kp) { ob.x = 0.f; ob.y = 0.f; ob.z = 0.f; ob.w = 0.f; }
    ((float4*)out)[r] = ob;               // proposals * keep
    out[55296 + r] = kp ? 1.0f : 0.0f;    // keep mask
  }
}

// ============================================================================
extern "C" void kernel_launch(void* const* d_in, const int* in_sizes, int n_in,
                              void* d_out, int out_size, void* d_ws, size_t ws_size,
                              hipStream_t stream)
{
  const float* feat   = (const float*)d_in[0];
  const int*   imgsz  = (const int*)d_in[1];
  const float* conv_w = (const float*)d_in[2];
  const float* conv_b = (const float*)d_in[3];
  const float* cls_w  = (const float*)d_in[4];
  const float* cls_b  = (const float*)d_in[5];
  const float* bbox_w = (const float*)d_in[6];
  const float* bbox_b = (const float*)d_in[7];
  float* out  = (float*)d_out;
  float* ws   = (float*)d_ws;
  float* x     = ws + WS_X_OFF;
  float* bbox  = ws + WS_BBOX_OFF;
  float* props = ws + WS_PROP_OFF;

  hipLaunchKernelGGL(conv3x3_relu_k, dim3(512), dim3(256), 0, stream,
                     feat, conv_w, conv_b, x);
  hipLaunchKernelGGL(head1x1_k, dim3(216), dim3(256), 0, stream,
                     x, cls_w, cls_b, bbox_w, bbox_b, out, bbox);
  hipLaunchKernelGGL(proposals_k, dim3(36), dim3(256), 0, stream,
                     bbox, imgsz, props);
  hipLaunchKernelGGL(nms_k, dim3(1), dim3(1024), 0, stream,
                     props, out);
}